// Round 9
// baseline (105.278 us; speedup 1.0000x reference)
//
#include <hip/hip_runtime.h>

#define NLAT 192
#define NPTS 40320
#define MMAX 96
#define LMAX 96
#define NV   100
#define MAXN 400
#define NB   400   // total B rows = 4 * NV

typedef __attribute__((ext_vector_type(8))) short short8v;  // 8 bf16 (4 VGPRs)
typedef __attribute__((ext_vector_type(4))) float f32x4;

#define FSTR 40   // K2 LDS row stride (shorts)

static __device__ __forceinline__ float bits2f(unsigned int b) {
    union { unsigned int i; float f; } v; v.i = b; return v.f;
}
static __device__ __forceinline__ unsigned int f2bf(float f) {
    union { float f; unsigned int i; } v; v.f = f;
    return (v.i + 0x7FFFu + ((v.i >> 16) & 1u)) >> 16;
}

// S(n) = sum_{t<n} floor(t/8)
static __device__ __forceinline__ int Ssum(int n) {
    int q = n >> 3, r = n & 7; return 4 * q * (q - 1) + q * r;
}
// padded-32 k-units before ring j in At (ragged layout); total = 43008
static __device__ __forceinline__ int atoffk(int j) {
    if (j < 96) return 32 * (Ssum(j + 12) - 4);
    return 32 * (672 + 676 - Ssum(204 - j));
}
static __device__ __forceinline__ int kpad_of(int j) {
    return 32 * ((j < 96 ? (j + 12) : (203 - j)) >> 3);
}

typedef const __attribute__((address_space(1))) void* gas_ptr;
typedef __attribute__((address_space(3))) void* las_ptr;
static __device__ __forceinline__ void gload_lds16(const void* g, void* l) {
    __builtin_amdgcn_global_load_lds((gas_ptr)g, (las_ptr)l, 16, 0, 0);
}

// ---------------- K0a: split leg fp32 -> bf16 hi/lo, relayout [l][m][j] -> [m][l][j]
__global__ __launch_bounds__(256) void leg_conv_kernel(
    const float* __restrict__ leg,    // [96 l][96 m][192 j]
    unsigned short* __restrict__ legh,
    unsigned short* __restrict__ legl)
{
    int idx = blockIdx.x * 256 + threadIdx.x;
    if (idx >= 96 * 96 * 192) return;
    int j = idx % 192;
    int lm = idx / 192;
    int m = lm % 96, l = lm / 96;
    float v = leg[idx];
    unsigned int h = f2bf(v);
    unsigned int lo = f2bf(v - bits2f(h << 16));
    size_t o = ((size_t)m * 96 + l) * 192 + j;
    legh[o] = (unsigned short)h;
    legl[o] = (unsigned short)lo;
}

// ---------------- K0b: transpose dft words into At[j][192 mm][kpad] bf16
// (mm = m for re, 96+m for im; k padded to x32 with zeros)
__global__ __launch_bounds__(256) void dft_transpose_kernel(
    const unsigned int* __restrict__ dftw,   // [192][400][96] (re | im<<16)
    unsigned short* __restrict__ At)
{
    const int j = blockIdx.x;
    const int kpad = kpad_of(j);
    const int k0 = blockIdx.y * 32;
    if (k0 >= kpad) return;
    const int n = j < 96 ? 20 + 4 * j : 400 - 4 * (j - 96);
    unsigned short* abase = At + (size_t)atoffk(j) * 192;
    const int tid = threadIdx.x;
#pragma unroll
    for (int s = 0; s < 3; ++s) {
        int slot = s * 256 + tid;          // 768 = 192 rows x 4 chunks
        int row = slot % 192;              // row-fastest: coalesced dft reads
        int ch  = slot / 192;
        int m = row < 96 ? row : row - 96;
        bool isIm = row >= 96;
        const unsigned int* dp = dftw + ((size_t)j * MAXN + k0 + ch * 8) * 96 + m;
        unsigned short o[8];
#pragma unroll
        for (int i = 0; i < 8; ++i) {
            int k = k0 + ch * 8 + i;
            unsigned int v = (k < n) ? dp[(size_t)i * 96] : 0u;
            o[i] = isIm ? (unsigned short)(v >> 16) : (unsigned short)(v & 0xFFFFu);
        }
        uint4 pk;
        pk.x = (unsigned int)o[0] | ((unsigned int)o[1] << 16);
        pk.y = (unsigned int)o[2] | ((unsigned int)o[3] << 16);
        pk.z = (unsigned int)o[4] | ((unsigned int)o[5] << 16);
        pk.w = (unsigned int)o[6] | ((unsigned int)o[7] << 16);
        *(uint4*)(abase + (size_t)row * kpad + k0 + ch * 8) = pk;
    }
}

// ---------------- K1 (MFMA): ring DFT GEMM, DMA-fed A, swizzled LDS.
// fh_hi/lo[j][mm][B] = sum_k At[j][mm][k] * x[B][k] (hi+lo split on x)
// LDS rows 64B; phys chunk = logical ^ ((row>>1)&3)  -> conflict-free b128.
__global__ __launch_bounds__(256, 4) void dft_mfma_kernel(
    const float* __restrict__ data,          // [4][NPTS][NV] fp32
    const unsigned short* __restrict__ At,   // ragged [j][192][kpad]
    unsigned short* __restrict__ fh_hi,      // [NLAT][192][cn] bf16
    unsigned short* __restrict__ fh_lo,
    int c0, int cn)
{
    __shared__ unsigned short A_lds[192 * 32];
    __shared__ unsigned short Xh_lds[64 * 32];
    __shared__ unsigned short Xl_lds[64 * 32];

    const int bt  = blockIdx.x;              // 50-col B tile
    const int p   = blockIdx.y;              // ring pair
    const int tid = threadIdx.x;
    const int w   = tid >> 6;
    const int l   = tid & 63;
    const int lr  = l & 15;
    const int kg  = l >> 4;
    const int kgp = kg ^ ((lr >> 1) & 3);    // swizzled frag chunk

    const int Bb = c0 + bt * 50;
    const int bb = Bb / NV;
    const int vb = Bb % NV;
    const float* dbase = data + (size_t)bb * NPTS * NV + vb;

    const int xc  = tid >> 2;                // X staging: B col 0..63
    const int xch = tid & 3;                 // logical k chunk
    const int xpc = xch ^ ((xc >> 1) & 3);   // phys chunk

    for (int rr = 0; rr < 2; ++rr) {
        int j, n, start;
        if (rr == 0) { j = p;      n = 20 + 4 * p;  start = 2 * p * p + 18 * p; }
        else         { j = 96 + p; n = 400 - 4 * p; start = 20160 + 402 * p - 2 * p * p; }
        const int kpad = kpad_of(j);
        const unsigned short* abase = At + (size_t)atoffk(j) * 192;

        f32x4 acc[3][4];
#pragma unroll
        for (int i = 0; i < 3; ++i)
#pragma unroll
            for (int nt = 0; nt < 4; ++nt) acc[i][nt] = (f32x4){0.f, 0.f, 0.f, 0.f};

        for (int k0 = 0; k0 < kpad; k0 += 32) {
            __syncthreads();   // protect previous step's frag reads

            // A: 3 DMA issues; per-lane source carries the XOR swizzle,
            // LDS dest is linear (wave-uniform base + lane*16).
#pragma unroll
            for (int s = 0; s < 3; ++s) {
                int slot = s * 256 + tid;
                int row  = slot >> 2;
                int chL  = (slot & 3) ^ ((row >> 1) & 3);
                const unsigned short* g = abase + (size_t)row * kpad + k0 + chL * 8;
                gload_lds16(g, &A_lds[s * 2048 + w * 512]);
            }

            // X: 8 fp32 loads -> hi (trunc, v_perm pack) + lo (cvt_pk RNE), b128 writes
            float xv[8];
            {
                const float* sp = dbase + (size_t)(start + k0 + xch * 8) * NV + xc;
#pragma unroll
                for (int i = 0; i < 8; ++i) {
                    int k = k0 + xch * 8 + i;
                    xv[i] = (xc < 50 && k < n) ? sp[(size_t)i * NV] : 0.f;
                }
            }
            unsigned int hi4[4], lo4[4];
#pragma unroll
            for (int t2 = 0; t2 < 4; ++t2) {
                unsigned int x0 = __float_as_uint(xv[2 * t2]);
                unsigned int x1 = __float_as_uint(xv[2 * t2 + 1]);
                hi4[t2] = __builtin_amdgcn_perm(x1, x0, 0x07060302u);
                float r0 = xv[2 * t2]     - bits2f(x0 & 0xFFFF0000u);
                float r1 = xv[2 * t2 + 1] - bits2f(x1 & 0xFFFF0000u);
                unsigned int pk;
                asm("v_cvt_pk_bf16_f32 %0, %1, %2" : "=v"(pk) : "v"(r0), "v"(r1));
                lo4[t2] = pk;
            }
            *(uint4*)&Xh_lds[xc * 32 + xpc * 8] = (uint4){hi4[0], hi4[1], hi4[2], hi4[3]};
            *(uint4*)&Xl_lds[xc * 32 + xpc * 8] = (uint4){lo4[0], lo4[1], lo4[2], lo4[3]};
            __syncthreads();   // drains vmcnt (DMA) + lgkmcnt

            short8v a0 = *(const short8v*)&A_lds[((3 * w + 0) * 16 + lr) * 32 + kgp * 8];
            short8v a1 = *(const short8v*)&A_lds[((3 * w + 1) * 16 + lr) * 32 + kgp * 8];
            short8v a2 = *(const short8v*)&A_lds[((3 * w + 2) * 16 + lr) * 32 + kgp * 8];
#pragma unroll
            for (int nt = 0; nt < 4; ++nt) {
                short8v bh = *(const short8v*)&Xh_lds[(nt * 16 + lr) * 32 + kgp * 8];
                short8v bl = *(const short8v*)&Xl_lds[(nt * 16 + lr) * 32 + kgp * 8];
                acc[0][nt] = __builtin_amdgcn_mfma_f32_16x16x32_bf16(a0, bh, acc[0][nt], 0, 0, 0);
                acc[1][nt] = __builtin_amdgcn_mfma_f32_16x16x32_bf16(a1, bh, acc[1][nt], 0, 0, 0);
                acc[2][nt] = __builtin_amdgcn_mfma_f32_16x16x32_bf16(a2, bh, acc[2][nt], 0, 0, 0);
                acc[0][nt] = __builtin_amdgcn_mfma_f32_16x16x32_bf16(a0, bl, acc[0][nt], 0, 0, 0);
                acc[1][nt] = __builtin_amdgcn_mfma_f32_16x16x32_bf16(a1, bl, acc[1][nt], 0, 0, 0);
                acc[2][nt] = __builtin_amdgcn_mfma_f32_16x16x32_bf16(a2, bl, acc[2][nt], 0, 0, 0);
            }
        }

        // epilogue: C/D col=lane&15 (B), row=(lane>>4)*4+reg (mm); emit bf16 hi+lo
#pragma unroll
        for (int i = 0; i < 3; ++i)
#pragma unroll
            for (int nt = 0; nt < 4; ++nt) {
                int c = nt * 16 + lr;
                if (c < 50) {
                    int Brel = bt * 50 + c;
                    int mm0 = (3 * w + i) * 16 + kg * 4;
                    unsigned short* oh = fh_hi + ((size_t)j * 192 + mm0) * cn + Brel;
                    unsigned short* ol = fh_lo + ((size_t)j * 192 + mm0) * cn + Brel;
#pragma unroll
                    for (int r = 0; r < 4; ++r) {
                        float v = acc[i][nt][r];
                        unsigned int h = f2bf(v);
                        unsigned int lo = f2bf(v - bits2f(h << 16));
                        oh[(size_t)r * cn] = (unsigned short)h;
                        ol[(size_t)r * cn] = (unsigned short)lo;
                    }
                }
            }
    }
}

// ---------------- K2 (MFMA): Legendre contraction as bf16 GEMM per m.
__global__ __launch_bounds__(256) void leg_mfma_kernel(
    const unsigned short* __restrict__ legh,  // [96 m][96 l][192 j] bf16
    const unsigned short* __restrict__ legl,
    const unsigned short* __restrict__ fh_hi, // [192 j][192 mm][cn] bf16
    const unsigned short* __restrict__ fh_lo,
    unsigned int* __restrict__ out,           // [4][LMAX][MMAX][NV] packed bf16
    int c0, int cn)
{
    __shared__ unsigned short A_lds[2 * 96 * FSTR];       // [hl][l][k]
    __shared__ unsigned short F_lds[2 * 2 * 64 * FSTR];   // [pl][hl][B][k]

    const int m   = blockIdx.x;
    const int bt  = blockIdx.y;
    const int tid = threadIdx.x;
    const int w   = tid >> 6;
    const int l   = tid & 63;
    const int lr  = l & 15;
    const int kg  = l >> 4;

    f32x4 acc[6][2];
#pragma unroll
    for (int lt = 0; lt < 6; ++lt)
#pragma unroll
        for (int pl = 0; pl < 2; ++pl) acc[lt][pl] = (f32x4){0.f, 0.f, 0.f, 0.f};

    const unsigned int* lh32 = (const unsigned int*)legh;
    const unsigned int* ll32 = (const unsigned int*)legl;

    for (int j0 = 0; j0 < NLAT; j0 += 32) {
        __syncthreads();

        // stage A: [2 hl][96 l][32 k]; s<6 -> hi plane, s>=6 -> lo (6*256=1536)
#pragma unroll
        for (int s = 0; s < 12; ++s) {
            const int hl = (s >= 6) ? 1 : 0;
            int rem = tid + 256 * s - 1536 * hl;   // 0..1535
            int lrow = rem >> 4;
            int ku = rem & 15;
            const unsigned int* src = hl ? ll32 : lh32;
            unsigned int v = src[((size_t)m * 96 + lrow) * 96 + (j0 >> 1) + ku];
            ((unsigned int*)A_lds)[(size_t)hl * 96 * (FSTR / 2) + lrow * (FSTR / 2) + ku] = v;
        }

        // stage F: [2 pl][2 hl][64 B][32 k]
#pragma unroll
        for (int s = 0; s < 13; ++s) {
            int q = tid + 256 * s;
            if (q < 3200) {
                int u  = q % 25;
                int r2 = q / 25;
                int jj = r2 & 31;
                int r3 = r2 >> 5;
                int pl = r3 & 1;
                int hl = r3 >> 1;
                const unsigned short* src = hl ? fh_lo : fh_hi;
                const unsigned int* s32 = (const unsigned int*)src;
                unsigned int v = s32[((size_t)(j0 + jj) * 192 + m + 96 * pl) * (cn >> 1)
                                     + bt * 25 + u];
                size_t base = ((size_t)(pl * 2 + hl) * 64 + 2 * u) * FSTR + jj;
                F_lds[base]        = (unsigned short)(v & 0xFFFFu);
                F_lds[base + FSTR] = (unsigned short)(v >> 16);
            }
        }
        __syncthreads();

        short8v fH[2], fL[2];
#pragma unroll
        for (int pl = 0; pl < 2; ++pl) {
            fH[pl] = *(const short8v*)&F_lds[((size_t)(pl * 2 + 0) * 64 + w * 16 + lr) * FSTR + kg * 8];
            fL[pl] = *(const short8v*)&F_lds[((size_t)(pl * 2 + 1) * 64 + w * 16 + lr) * FSTR + kg * 8];
        }
#pragma unroll
        for (int lt = 0; lt < 6; ++lt) {
            short8v ah = *(const short8v*)&A_lds[(size_t)(0 * 96 + lt * 16 + lr) * FSTR + kg * 8];
            short8v al = *(const short8v*)&A_lds[(size_t)(1 * 96 + lt * 16 + lr) * FSTR + kg * 8];
#pragma unroll
            for (int pl = 0; pl < 2; ++pl) {
                acc[lt][pl] = __builtin_amdgcn_mfma_f32_16x16x32_bf16(ah, fH[pl], acc[lt][pl], 0, 0, 0);
                acc[lt][pl] = __builtin_amdgcn_mfma_f32_16x16x32_bf16(ah, fL[pl], acc[lt][pl], 0, 0, 0);
                acc[lt][pl] = __builtin_amdgcn_mfma_f32_16x16x32_bf16(al, fH[pl], acc[lt][pl], 0, 0, 0);
            }
        }
    }

    int c = w * 16 + lr;
    if (c < 50) {
        int B = c0 + bt * 50 + c;
        int bb = B / NV, vv = B % NV;
#pragma unroll
        for (int lt = 0; lt < 6; ++lt) {
#pragma unroll
            for (int r = 0; r < 4; ++r) {
                int ll = lt * 16 + kg * 4 + r;
                out[(((size_t)bb * LMAX + ll) * MMAX + m) * NV + vv] =
                    f2bf(acc[lt][0][r]) | (f2bf(acc[lt][1][r]) << 16);
            }
        }
    }
}

extern "C" void kernel_launch(void* const* d_in, const int* in_sizes, int n_in,
                              void* d_out, int out_size, void* d_ws, size_t ws_size,
                              hipStream_t stream) {
    if (n_in != 3) return;

    const float* data = (const float*)d_in[0];
    const unsigned int* dftw = (const unsigned int*)d_in[1];
    const float* leg  = (const float*)d_in[2];
    unsigned int* out = (unsigned int*)d_out;

    // ws: [legh][legl][At][fh_hi][fh_lo]
    const size_t LEGN = (size_t)96 * 96 * 192;
    const size_t LEGB = 2 * LEGN * sizeof(unsigned short);   // 7.08 MB
    const size_t ATN  = (size_t)43008 * 192;                 // shorts
    const size_t ATB  = ATN * sizeof(unsigned short);        // 16.5 MB
    const size_t rowb = (size_t)192 * 192 * 2 * sizeof(unsigned short); // per B row
    if (ws_size < LEGB + ATB + 50 * rowb) return;

    unsigned short* legh = (unsigned short*)d_ws;
    unsigned short* legl = legh + LEGN;
    unsigned short* At   = legl + LEGN;

    size_t maxrows = (ws_size - LEGB - ATB) / rowb;
    int chunk = (int)((maxrows / 50) * 50);
    if (chunk > NB) chunk = NB;

    leg_conv_kernel<<<dim3((96 * 96 * 192 + 255) / 256), dim3(256), 0, stream>>>(
        leg, legh, legl);
    dft_transpose_kernel<<<dim3(192, 13), dim3(256), 0, stream>>>(dftw, At);

    for (int c0 = 0; c0 < NB; c0 += chunk) {
        int cn = NB - c0 < chunk ? NB - c0 : chunk;
        unsigned short* fh_hi = At + ATN;
        unsigned short* fh_lo = fh_hi + (size_t)192 * 192 * cn;

        dim3 g1(cn / 50, 96);
        dft_mfma_kernel<<<g1, dim3(256), 0, stream>>>(data, At, fh_hi, fh_lo, c0, cn);
        dim3 g2(96, cn / 50);
        leg_mfma_kernel<<<g2, dim3(256), 0, stream>>>(legh, legl, fh_hi, fh_lo, out, c0, cn);
    }
}

// Round 10
// 87.081 us; speedup vs baseline: 1.2090x; 1.2090x over previous
//
#include <hip/hip_runtime.h>

#define NLAT 192
#define NPTS 40320
#define MMAX 96
#define LMAX 96
#define NV   100
#define MAXN 400
#define NB   400   // total B rows = 4 * NV

typedef __attribute__((ext_vector_type(8))) short short8v;  // 8 bf16 (4 VGPRs)
typedef __attribute__((ext_vector_type(4))) float f32x4;

#define FSTR 40   // K2 LDS row stride (shorts)

static __device__ __forceinline__ float bits2f(unsigned int b) {
    union { unsigned int i; float f; } v; v.i = b; return v.f;
}
static __device__ __forceinline__ unsigned int f2bf(float f) {
    union { float f; unsigned int i; } v; v.f = f;
    return (v.i + 0x7FFFu + ((v.i >> 16) & 1u)) >> 16;
}

// S(n) = sum_{t<n} floor(t/8)
static __device__ __forceinline__ int Ssum(int n) {
    int q = n >> 3, r = n & 7; return 4 * q * (q - 1) + q * r;
}
// padded-32 k-units before ring j in At (ragged layout); total = 43008
static __device__ __forceinline__ int atoffk(int j) {
    if (j < 96) return 32 * (Ssum(j + 12) - 4);
    return 32 * (672 + 676 - Ssum(204 - j));
}
static __device__ __forceinline__ int kpad_of(int j) {
    return 32 * ((j < 96 ? (j + 12) : (203 - j)) >> 3);
}

typedef const __attribute__((address_space(1))) void* gas_ptr;
typedef __attribute__((address_space(3))) void* las_ptr;
static __device__ __forceinline__ void gload_lds16(const void* g, void* l) {
    __builtin_amdgcn_global_load_lds((gas_ptr)g, (las_ptr)l, 16, 0, 0);
}

// ---------------- K0a: split leg fp32 -> bf16 hi/lo, relayout [l][m][j] -> [m][l][j]
__global__ __launch_bounds__(256) void leg_conv_kernel(
    const float* __restrict__ leg,    // [96 l][96 m][192 j]
    unsigned short* __restrict__ legh,
    unsigned short* __restrict__ legl)
{
    int idx = blockIdx.x * 256 + threadIdx.x;
    if (idx >= 96 * 96 * 192) return;
    int j = idx % 192;
    int lm = idx / 192;
    int m = lm % 96, l = lm / 96;
    float v = leg[idx];
    unsigned int h = f2bf(v);
    unsigned int lo = f2bf(v - bits2f(h << 16));
    size_t o = ((size_t)m * 96 + l) * 192 + j;
    legh[o] = (unsigned short)h;
    legl[o] = (unsigned short)lo;
}

// ---------------- K0b: transpose dft words into At, k-step-blocked layout:
// At[j]: for each k-step t, contiguous [192 rows][32 k] bf16 (12288 B)
// rows: mm = m (re) / 96+m (im); k padded to x32 with zeros. NO swizzle in memory.
__global__ __launch_bounds__(256) void dft_transpose_kernel(
    const unsigned int* __restrict__ dftw,   // [192][400][96] (re | im<<16)
    unsigned short* __restrict__ At)
{
    const int j = blockIdx.x;
    const int kpad = kpad_of(j);
    const int t = blockIdx.y;
    const int k0 = t * 32;
    if (k0 >= kpad) return;
    const int n = j < 96 ? 20 + 4 * j : 400 - 4 * (j - 96);
    unsigned short* abase = At + (size_t)atoffk(j) * 192 + (size_t)t * 6144;
    const int tid = threadIdx.x;
#pragma unroll
    for (int s = 0; s < 3; ++s) {
        int slot = s * 256 + tid;          // 768 = 192 rows x 4 chunks
        int row = slot % 192;              // row-fastest: coalesced dft reads
        int ch  = slot / 192;
        int m = row < 96 ? row : row - 96;
        bool isIm = row >= 96;
        const unsigned int* dp = dftw + ((size_t)j * MAXN + k0 + ch * 8) * 96 + m;
        unsigned short o[8];
#pragma unroll
        for (int i = 0; i < 8; ++i) {
            int k = k0 + ch * 8 + i;
            unsigned int v = (k < n) ? dp[(size_t)i * 96] : 0u;
            o[i] = isIm ? (unsigned short)(v >> 16) : (unsigned short)(v & 0xFFFFu);
        }
        uint4 pk;
        pk.x = (unsigned int)o[0] | ((unsigned int)o[1] << 16);
        pk.y = (unsigned int)o[2] | ((unsigned int)o[3] << 16);
        pk.z = (unsigned int)o[4] | ((unsigned int)o[5] << 16);
        pk.w = (unsigned int)o[6] | ((unsigned int)o[7] << 16);
        *(uint4*)(abase + (size_t)row * 32 + ch * 8) = pk;
    }
}

// ---------------- K1 (MFMA): ring DFT GEMM, 2-phase pipelined, DMA-fed A.
// fh_hi/lo[j][mm][B] = sum_k At[j][mm][k] * x[B][k] (hi+lo split on x)
// Grid 1-D: j = id%192 (same-ring blocks land on same XCD: 192 % 8 == 0),
// bt = id/192. Double-buffered LDS; XOR swizzle baked into DMA source addr.
__global__ __launch_bounds__(256, 4) void dft_mfma_kernel(
    const float* __restrict__ data,          // [4][NPTS][NV] fp32
    const unsigned short* __restrict__ At,   // ragged [j][t][192][32]
    unsigned short* __restrict__ fh_hi,      // [NLAT][192][cn] bf16
    unsigned short* __restrict__ fh_lo,
    int c0, int cn)
{
    __shared__ unsigned short A_lds[2][192 * 32];
    __shared__ unsigned short Xh_lds[2][64 * 32];
    __shared__ unsigned short Xl_lds[2][64 * 32];

    const int id  = blockIdx.x;
    const int j   = id % 192;
    const int bt  = id / 192;
    const int tid = threadIdx.x;
    const int w   = tid >> 6;
    const int l   = tid & 63;
    const int lr  = l & 15;
    const int kg  = l >> 4;
    const int kgp = kg ^ ((lr >> 1) & 3);    // swizzled frag chunk

    int n, start;
    if (j < 96) { n = 20 + 4 * j; start = 2 * j * j + 18 * j; }
    else { int jj = j - 96; n = 400 - 4 * jj; start = 20160 + 402 * jj - 2 * jj * jj; }
    const int nsteps = kpad_of(j) >> 5;
    const unsigned short* abase = At + (size_t)atoffk(j) * 192;

    const int Bb = c0 + bt * 50;
    const int bb = Bb / NV;
    const int vb = Bb % NV;
    const float* dbase = data + (size_t)bb * NPTS * NV + vb;

    const int xc  = tid >> 2;                // X staging: B col 0..63
    const int xch = tid & 3;                 // logical k chunk
    const int xpc = xch ^ ((xc >> 1) & 3);   // phys chunk

    f32x4 acc[3][4];
#pragma unroll
    for (int i = 0; i < 3; ++i)
#pragma unroll
        for (int nt = 0; nt < 4; ++nt) acc[i][nt] = (f32x4){0.f, 0.f, 0.f, 0.f};

    float xv[8];

    // ---- prologue: stage step 0 into buf 0
    {
        const float* sp = dbase + (size_t)(start + xch * 8) * NV + xc;
#pragma unroll
        for (int i = 0; i < 8; ++i) {
            int k = xch * 8 + i;
            xv[i] = (xc < 50 && k < n) ? sp[(size_t)i * NV] : 0.f;
        }
#pragma unroll
        for (int s = 0; s < 3; ++s) {
            int slot = s * 256 + tid;
            int row  = slot >> 2;
            int chs  = (slot & 3) ^ ((row >> 1) & 3);
            gload_lds16(abase + (size_t)row * 32 + chs * 8, &A_lds[0][s * 2048 + w * 512]);
        }
        unsigned int hi4[4], lo4[4];
#pragma unroll
        for (int t2 = 0; t2 < 4; ++t2) {
            unsigned int x0 = __float_as_uint(xv[2 * t2]);
            unsigned int x1 = __float_as_uint(xv[2 * t2 + 1]);
            hi4[t2] = __builtin_amdgcn_perm(x1, x0, 0x07060302u);
            float r0 = xv[2 * t2]     - bits2f(x0 & 0xFFFF0000u);
            float r1 = xv[2 * t2 + 1] - bits2f(x1 & 0xFFFF0000u);
            unsigned int pk;
            asm("v_cvt_pk_bf16_f32 %0, %1, %2" : "=v"(pk) : "v"(r0), "v"(r1));
            lo4[t2] = pk;
        }
        *(uint4*)&Xh_lds[0][xc * 32 + xpc * 8] = (uint4){hi4[0], hi4[1], hi4[2], hi4[3]};
        *(uint4*)&Xl_lds[0][xc * 32 + xpc * 8] = (uint4){lo4[0], lo4[1], lo4[2], lo4[3]};
        __syncthreads();   // drains DMA (vmcnt) + ds_writes (lgkmcnt)
    }

    int buf = 0;
    for (int t = 0; t < nsteps; ++t) {
        const int nb = buf ^ 1;
        const bool pf = (t + 1 < nsteps);

        // ---- issue next-step staging BEFORE compute (latency hides under MFMA)
        if (pf) {
            const float* sp = dbase + (size_t)(start + (t + 1) * 32 + xch * 8) * NV + xc;
#pragma unroll
            for (int i = 0; i < 8; ++i) {
                int k = (t + 1) * 32 + xch * 8 + i;
                xv[i] = (xc < 50 && k < n) ? sp[(size_t)i * NV] : 0.f;
            }
#pragma unroll
            for (int s = 0; s < 3; ++s) {
                int slot = s * 256 + tid;
                int row  = slot >> 2;
                int chs  = (slot & 3) ^ ((row >> 1) & 3);
                gload_lds16(abase + (size_t)(t + 1) * 6144 + row * 32 + chs * 8,
                            &A_lds[nb][s * 2048 + w * 512]);
            }
        }

        // ---- compute current step from buf
        short8v a0 = *(const short8v*)&A_lds[buf][((3 * w + 0) * 16 + lr) * 32 + kgp * 8];
        short8v a1 = *(const short8v*)&A_lds[buf][((3 * w + 1) * 16 + lr) * 32 + kgp * 8];
        short8v a2 = *(const short8v*)&A_lds[buf][((3 * w + 2) * 16 + lr) * 32 + kgp * 8];
#pragma unroll
        for (int nt = 0; nt < 4; ++nt) {
            short8v bh = *(const short8v*)&Xh_lds[buf][(nt * 16 + lr) * 32 + kgp * 8];
            short8v bl = *(const short8v*)&Xl_lds[buf][(nt * 16 + lr) * 32 + kgp * 8];
            acc[0][nt] = __builtin_amdgcn_mfma_f32_16x16x32_bf16(a0, bh, acc[0][nt], 0, 0, 0);
            acc[1][nt] = __builtin_amdgcn_mfma_f32_16x16x32_bf16(a1, bh, acc[1][nt], 0, 0, 0);
            acc[2][nt] = __builtin_amdgcn_mfma_f32_16x16x32_bf16(a2, bh, acc[2][nt], 0, 0, 0);
            acc[0][nt] = __builtin_amdgcn_mfma_f32_16x16x32_bf16(a0, bl, acc[0][nt], 0, 0, 0);
            acc[1][nt] = __builtin_amdgcn_mfma_f32_16x16x32_bf16(a1, bl, acc[1][nt], 0, 0, 0);
            acc[2][nt] = __builtin_amdgcn_mfma_f32_16x16x32_bf16(a2, bl, acc[2][nt], 0, 0, 0);
        }

        // ---- convert+write next-step X into nb (after MFMA reads of buf)
        if (pf) {
            unsigned int hi4[4], lo4[4];
#pragma unroll
            for (int t2 = 0; t2 < 4; ++t2) {
                unsigned int x0 = __float_as_uint(xv[2 * t2]);
                unsigned int x1 = __float_as_uint(xv[2 * t2 + 1]);
                hi4[t2] = __builtin_amdgcn_perm(x1, x0, 0x07060302u);
                float r0 = xv[2 * t2]     - bits2f(x0 & 0xFFFF0000u);
                float r1 = xv[2 * t2 + 1] - bits2f(x1 & 0xFFFF0000u);
                unsigned int pk;
                asm("v_cvt_pk_bf16_f32 %0, %1, %2" : "=v"(pk) : "v"(r0), "v"(r1));
                lo4[t2] = pk;
            }
            *(uint4*)&Xh_lds[nb][xc * 32 + xpc * 8] = (uint4){hi4[0], hi4[1], hi4[2], hi4[3]};
            *(uint4*)&Xl_lds[nb][xc * 32 + xpc * 8] = (uint4){lo4[0], lo4[1], lo4[2], lo4[3]};
        }
        __syncthreads();   // one barrier per k-step: drains DMA + ds_writes
        buf = nb;
    }

    // ---- epilogue: C/D col=lane&15 (B), row=(lane>>4)*4+reg (mm); emit bf16 hi+lo
#pragma unroll
    for (int i = 0; i < 3; ++i)
#pragma unroll
        for (int nt = 0; nt < 4; ++nt) {
            int c = nt * 16 + lr;
            if (c < 50) {
                int Brel = bt * 50 + c;
                int mm0 = (3 * w + i) * 16 + kg * 4;
                unsigned short* oh = fh_hi + ((size_t)j * 192 + mm0) * cn + Brel;
                unsigned short* ol = fh_lo + ((size_t)j * 192 + mm0) * cn + Brel;
#pragma unroll
                for (int r = 0; r < 4; ++r) {
                    float v = acc[i][nt][r];
                    unsigned int h = f2bf(v);
                    unsigned int lo = f2bf(v - bits2f(h << 16));
                    oh[(size_t)r * cn] = (unsigned short)h;
                    ol[(size_t)r * cn] = (unsigned short)lo;
                }
            }
        }
}

// ---------------- K2 (MFMA): Legendre contraction as bf16 GEMM per m.
__global__ __launch_bounds__(256) void leg_mfma_kernel(
    const unsigned short* __restrict__ legh,  // [96 m][96 l][192 j] bf16
    const unsigned short* __restrict__ legl,
    const unsigned short* __restrict__ fh_hi, // [192 j][192 mm][cn] bf16
    const unsigned short* __restrict__ fh_lo,
    unsigned int* __restrict__ out,           // [4][LMAX][MMAX][NV] packed bf16
    int c0, int cn)
{
    __shared__ unsigned short A_lds[2 * 96 * FSTR];       // [hl][l][k]
    __shared__ unsigned short F_lds[2 * 2 * 64 * FSTR];   // [pl][hl][B][k]

    const int m   = blockIdx.x;
    const int bt  = blockIdx.y;
    const int tid = threadIdx.x;
    const int w   = tid >> 6;
    const int l   = tid & 63;
    const int lr  = l & 15;
    const int kg  = l >> 4;

    f32x4 acc[6][2];
#pragma unroll
    for (int lt = 0; lt < 6; ++lt)
#pragma unroll
        for (int pl = 0; pl < 2; ++pl) acc[lt][pl] = (f32x4){0.f, 0.f, 0.f, 0.f};

    const unsigned int* lh32 = (const unsigned int*)legh;
    const unsigned int* ll32 = (const unsigned int*)legl;

    for (int j0 = 0; j0 < NLAT; j0 += 32) {
        __syncthreads();

        // stage A: [2 hl][96 l][32 k]; s<6 -> hi plane, s>=6 -> lo (6*256=1536)
#pragma unroll
        for (int s = 0; s < 12; ++s) {
            const int hl = (s >= 6) ? 1 : 0;
            int rem = tid + 256 * s - 1536 * hl;   // 0..1535
            int lrow = rem >> 4;
            int ku = rem & 15;
            const unsigned int* src = hl ? ll32 : lh32;
            unsigned int v = src[((size_t)m * 96 + lrow) * 96 + (j0 >> 1) + ku];
            ((unsigned int*)A_lds)[(size_t)hl * 96 * (FSTR / 2) + lrow * (FSTR / 2) + ku] = v;
        }

        // stage F: [2 pl][2 hl][64 B][32 k]
#pragma unroll
        for (int s = 0; s < 13; ++s) {
            int q = tid + 256 * s;
            if (q < 3200) {
                int u  = q % 25;
                int r2 = q / 25;
                int jj = r2 & 31;
                int r3 = r2 >> 5;
                int pl = r3 & 1;
                int hl = r3 >> 1;
                const unsigned short* src = hl ? fh_lo : fh_hi;
                const unsigned int* s32 = (const unsigned int*)src;
                unsigned int v = s32[((size_t)(j0 + jj) * 192 + m + 96 * pl) * (cn >> 1)
                                     + bt * 25 + u];
                size_t base = ((size_t)(pl * 2 + hl) * 64 + 2 * u) * FSTR + jj;
                F_lds[base]        = (unsigned short)(v & 0xFFFFu);
                F_lds[base + FSTR] = (unsigned short)(v >> 16);
            }
        }
        __syncthreads();

        short8v fH[2], fL[2];
#pragma unroll
        for (int pl = 0; pl < 2; ++pl) {
            fH[pl] = *(const short8v*)&F_lds[((size_t)(pl * 2 + 0) * 64 + w * 16 + lr) * FSTR + kg * 8];
            fL[pl] = *(const short8v*)&F_lds[((size_t)(pl * 2 + 1) * 64 + w * 16 + lr) * FSTR + kg * 8];
        }
#pragma unroll
        for (int lt = 0; lt < 6; ++lt) {
            short8v ah = *(const short8v*)&A_lds[(size_t)(0 * 96 + lt * 16 + lr) * FSTR + kg * 8];
            short8v al = *(const short8v*)&A_lds[(size_t)(1 * 96 + lt * 16 + lr) * FSTR + kg * 8];
#pragma unroll
            for (int pl = 0; pl < 2; ++pl) {
                acc[lt][pl] = __builtin_amdgcn_mfma_f32_16x16x32_bf16(ah, fH[pl], acc[lt][pl], 0, 0, 0);
                acc[lt][pl] = __builtin_amdgcn_mfma_f32_16x16x32_bf16(ah, fL[pl], acc[lt][pl], 0, 0, 0);
                acc[lt][pl] = __builtin_amdgcn_mfma_f32_16x16x32_bf16(al, fH[pl], acc[lt][pl], 0, 0, 0);
            }
        }
    }

    int c = w * 16 + lr;
    if (c < 50) {
        int B = c0 + bt * 50 + c;
        int bb = B / NV, vv = B % NV;
#pragma unroll
        for (int lt = 0; lt < 6; ++lt) {
#pragma unroll
            for (int r = 0; r < 4; ++r) {
                int ll = lt * 16 + kg * 4 + r;
                out[(((size_t)bb * LMAX + ll) * MMAX + m) * NV + vv] =
                    f2bf(acc[lt][0][r]) | (f2bf(acc[lt][1][r]) << 16);
            }
        }
    }
}

extern "C" void kernel_launch(void* const* d_in, const int* in_sizes, int n_in,
                              void* d_out, int out_size, void* d_ws, size_t ws_size,
                              hipStream_t stream) {
    if (n_in != 3) return;

    const float* data = (const float*)d_in[0];
    const unsigned int* dftw = (const unsigned int*)d_in[1];
    const float* leg  = (const float*)d_in[2];
    unsigned int* out = (unsigned int*)d_out;

    // ws: [legh][legl][At][fh_hi][fh_lo]
    const size_t LEGN = (size_t)96 * 96 * 192;
    const size_t LEGB = 2 * LEGN * sizeof(unsigned short);   // 7.08 MB
    const size_t ATN  = (size_t)43008 * 192;                 // shorts
    const size_t ATB  = ATN * sizeof(unsigned short);        // 16.5 MB
    const size_t rowb = (size_t)192 * 192 * 2 * sizeof(unsigned short); // per B row
    if (ws_size < LEGB + ATB + 50 * rowb) return;

    unsigned short* legh = (unsigned short*)d_ws;
    unsigned short* legl = legh + LEGN;
    unsigned short* At   = legl + LEGN;

    size_t maxrows = (ws_size - LEGB - ATB) / rowb;
    int chunk = (int)((maxrows / 50) * 50);
    if (chunk > NB) chunk = NB;

    leg_conv_kernel<<<dim3((96 * 96 * 192 + 255) / 256), dim3(256), 0, stream>>>(
        leg, legh, legl);
    dft_transpose_kernel<<<dim3(192, 13), dim3(256), 0, stream>>>(dftw, At);

    for (int c0 = 0; c0 < NB; c0 += chunk) {
        int cn = NB - c0 < chunk ? NB - c0 : chunk;
        unsigned short* fh_hi = At + ATN;
        unsigned short* fh_lo = fh_hi + (size_t)192 * 192 * cn;

        int nbt = cn / 50;
        dim3 g1(192 * nbt);
        dft_mfma_kernel<<<g1, dim3(256), 0, stream>>>(data, At, fh_hi, fh_lo, c0, cn);
        dim3 g2(96, nbt);
        leg_mfma_kernel<<<g2, dim3(256), 0, stream>>>(legh, legl, fh_hi, fh_lo, out, c0, cn);
    }
}